// Round 15
// baseline (110.608 us; speedup 1.0000x reference)
//
#include <hip/hip_runtime.h>
#include <hip/hip_cooperative_groups.h>

namespace cg = cooperative_groups;

// Histogram1D: triangular-kernel soft histogram, 100 bins over [0,1], row-normalized.
// x: [32, 1048576] f32. out: [32, 100] f32.
//
// Formulation (validated R3-R14): U = x*25600+128; iU=(int)U; r=iU>>8 in [0,100];
// cell(uint32) += 0x10000 | (iU&255)  (N in hi16, sum(floor(256w)) in lo16);
// counts[b] = N[b+1] - (W[b+1]-W[b])/256.  Native ds_add_u32 atomics (R11),
// pair-share conflict-free banking [wave][row][32 cols] (R14, bank = lane>>1).
//
// Measured walls (R12 instrumented + R14): scattered ds_add_u32 front-end
// ~29 cyc/wave-instr (~2.2 lanes/cyc, layout-insensitive; 2 lanes/bank is the
// 64-lane minimum) -> hist floor ~24.6us; blended L3+HBM read path ~5 TB/s
// -> ~25us. hist measured ~26us: within ~5% of floor. Remaining slack is the
// norm kernel + launch gap (~5us).
//
// Round-15: FUSE NORM via cooperative grid sync. Grid is exactly-resident
// (768 = 3/CU, LDS 51.7KB*3 <= 160KB), so this_grid().sync() is legal; after
// the barrier blocks 0..31 reduce 24 partials/row and write d_out. Kills the
// second dispatch + gap. Ticket fusion rejected: ws poison (0xAA) breaks any
// last-block counter on the first timed replay. Fallback two-kernel path if
// cooperative launch fails under graph capture.

#define BINS 100
#define ROWS 101
#define BATCH 32
#define NPER 1048576
#define TPB 256
#define WAVES 4
#define COLS 32
#define BPR 24                         // blocks per row
#define GRID (BATCH * BPR)             // 768 = 3 per CU, all resident
#define NF4_ROW (NPER / 4)             // 262144 float4 per row
#define STRIDE (BPR * TPB)             // 6144 f4 grid stride
#define HCELLS (WAVES * ROWS * COLS)   // 12928 dwords = 51.7 KB

typedef float f32x4 __attribute__((ext_vector_type(4)));

template <int FUSED>
__device__ __forceinline__ void hist_body(const float* __restrict__ x,
                                          float* __restrict__ partial,
                                          float* __restrict__ out) {
    __shared__ uint32_t h[HCELLS];
    const int tid = threadIdx.x;

    uint4* h4 = reinterpret_cast<uint4*>(h);
    for (int i = tid; i < HCELLS / 4; i += TPB) h4[i] = make_uint4(0, 0, 0, 0);
    __syncthreads();

    const int row  = blockIdx.x / BPR;
    const int jblk = blockIdx.x % BPR;
    const int wave = tid >> 6;
    const int col  = (tid & 63) >> 1;            // 2 lanes share a column
    uint32_t* hw = h + wave * (ROWS * COLS) + col;

    const f32x4* src = reinterpret_cast<const f32x4*>(x + (size_t)row * NPER);
    for (int i = jblk * TPB + tid; i < NF4_ROW; i += STRIDE) {
        f32x4 v = src[i];                        // cached vector load
#pragma unroll
        for (int e = 0; e < 4; ++e) {
            float U = __builtin_fmaf(v[e], 25600.0f, 128.0f);   // 256*(x*100+0.5)
            int  iU = (int)U;                                   // 128..25728
            int   r = iU >> 8;                                  // row 0..100
            uint32_t inc = 0x10000u | (uint32_t)(iU & 255);     // N=1 | Wfix
            atomicAdd(&hw[r * COLS], inc);       // ds_add_u32, bank = lane>>1
        }
    }
    __syncthreads();

    // Stage 1: per-(wave,row) sums over 32 cols (404 tasks; rotated col).
    uint32_t s0 = 0, s1 = 0;
    const int a0 = tid, a1 = tid + TPB;
    {
        int w = a0 / ROWS, r = a0 - w * ROWS;
        const uint32_t* base = h + w * (ROWS * COLS) + r * COLS;
        uint32_t s = 0;
#pragma unroll
        for (int c = 0; c < COLS; ++c) s += base[(c + tid) & (COLS - 1)];
        s0 = s;
    }
    if (a1 < WAVES * ROWS) {
        int w = a1 / ROWS, r = a1 - w * ROWS;
        const uint32_t* base = h + w * (ROWS * COLS) + r * COLS;
        uint32_t s = 0;
#pragma unroll
        for (int c = 0; c < COLS; ++c) s += base[(c + tid) & (COLS - 1)];
        s1 = s;
    }
    __syncthreads();
    // Stage 2: unpack task sums into reused h: N at [task], W at [512+task].
    h[a0] = s0 >> 16;
    h[512 + a0] = s0 & 0xFFFFu;
    if (a1 < WAVES * ROWS) { h[a1] = s1 >> 16; h[512 + a1] = s1 & 0xFFFFu; }
    __syncthreads();
    // Stage 3: per-row totals across the 4 waves.
    if (tid < ROWS) {
        uint32_t N = h[tid] + h[101 + tid] + h[202 + tid] + h[303 + tid];
        uint32_t W = h[512 + tid] + h[613 + tid] + h[714 + tid] + h[815 + tid];
        h[1024 + tid] = N;
        h[1536 + tid] = W;
    }
    __syncthreads();
    // Stage 4: counts[b] = N[b+1] - (W[b+1]-W[b])/256 -> partial store.
    if (tid < BINS) {
        float N1 = (float)h[1024 + tid + 1];
        float W1 = (float)h[1536 + tid + 1];
        float W0 = (float)h[1536 + tid];
        partial[blockIdx.x * BINS + tid] = N1 + (W0 - W1) * (1.0f / 256.0f);
    }

    if constexpr (FUSED) {
        cg::this_grid().sync();                  // all blocks reach this
        if (blockIdx.x < BATCH) {                // blocks 0..31: normalize row
            const int nrow = blockIdx.x;
            float* csum = reinterpret_cast<float*>(h);   // h is free now
            float cnt = 0.0f;
            if (tid < BINS) {
                const float* p = partial + (size_t)nrow * BPR * BINS + tid;
#pragma unroll
                for (int j = 0; j < BPR; ++j) cnt += p[j * BINS];
                csum[tid] = cnt;
            }
            __syncthreads();
            if (tid < 64) {                      // wave 0 reduces the row sum
                float s = csum[tid] + ((tid + 64 < BINS) ? csum[tid + 64] : 0.0f);
#pragma unroll
                for (int off = 32; off > 0; off >>= 1) s += __shfl_down(s, off);
                if (tid == 0) csum[BINS] = s;
            }
            __syncthreads();
            const float total = csum[BINS];
            if (tid < BINS)
                out[nrow * BINS + tid] = 0.01f * cnt / (0.01f * total + 1e-5f);
        }
    }
}

__global__ __launch_bounds__(TPB, 3) void hist_fused(const float* __restrict__ x,
                                                     float* __restrict__ partial,
                                                     float* __restrict__ out) {
    hist_body<1>(x, partial, out);
}

__global__ __launch_bounds__(TPB, 3) void hist_plain(const float* __restrict__ x,
                                                     float* __restrict__ partial,
                                                     float* __restrict__ out) {
    hist_body<0>(x, partial, out);
}

// Fallback normalize (only used if cooperative launch is unavailable).
__global__ __launch_bounds__(128) void norm_kernel(const float* __restrict__ partial,
                                                   float* __restrict__ out) {
    __shared__ float sarr[2];
    const int row = blockIdx.x;
    const int t   = threadIdx.x;
    float cnt = 0.0f;
    if (t < BINS) {
        const float* p = partial + (size_t)row * BPR * BINS + t;
#pragma unroll
        for (int j = 0; j < BPR; ++j) cnt += p[j * BINS];
    }
    float s = cnt;
#pragma unroll
    for (int off = 32; off > 0; off >>= 1) s += __shfl_down(s, off);
    if ((t & 63) == 0) sarr[t >> 6] = s;
    __syncthreads();
    const float total = sarr[0] + sarr[1];
    if (t < BINS) {
        out[row * BINS + t] = 0.01f * cnt / (0.01f * total + 1e-5f);
    }
}

extern "C" void kernel_launch(void* const* d_in, const int* in_sizes, int n_in,
                              void* d_out, int out_size, void* d_ws, size_t ws_size,
                              hipStream_t stream) {
    const float* x = (const float*)d_in[0];
    float* out = (float*)d_out;
    float* partial = (float*)d_ws;     // 768*100*4 = 307.2 KB

    void* args[] = {(void*)&x, (void*)&partial, (void*)&out};
    hipError_t e = hipLaunchCooperativeKernel((const void*)hist_fused,
                                              dim3(GRID), dim3(TPB),
                                              args, 0, stream);
    if (e != hipSuccess) {
        // deterministic fallback: two-dispatch path (no grid.sync executed)
        hist_plain<<<GRID, TPB, 0, stream>>>(x, partial, out);
        norm_kernel<<<BATCH, 128, 0, stream>>>(partial, out);
    }
}

// Round 16
// 31.642 us; speedup vs baseline: 3.4956x; 3.4956x over previous
//
#include <hip/hip_runtime.h>

// Histogram1D: triangular-kernel soft histogram, 100 bins over [0,1], row-normalized.
// x: [32, 1048576] f32. out: [32, 100] f32.
//
// FINAL STRUCTURE (= R14, the measured best at 30.9us; R15's cooperative
// grid-sync fusion ran the main loop 5x slower and is reverted).
//
// Formulation (validated R3-R14): U = x*25600+128; iU=(int)U; r=iU>>8 in [0,100];
// cell(uint32) += 0x10000 | (iU&255)  (N in hi16, sum(floor(256w)) in lo16);
// counts[b] = N[b+1] - (W[b+1]-W[b])/256.
//
// Measured walls (R12 instrumented; R7/R10/R11/R14 ladder):
//  - scattered ds_add_u32 ~30 cyc/wave-instr (~2.2 lanes/cyc), layout- and
//    occupancy-insensitive; 2048 instrs/CU -> ~25us. Scattered read+write
//    RMW variants land on the same total (DS pipe processes address-
//    divergent lanes at ~2-4/cyc regardless of structure).
//  - blended L3+HBM read path ~5.2 TB/s for 134MB -> ~25us (NT bypass
//    regressed it, R13; half the fetch is L3-hit, R12 FETCH=65MB/pass).
//  hist ~26us sits on both floors simultaneously. norm ~2us + gap ~3us.
//
// Key structure: native integer LDS atomics (fire-and-forget ds_add_u32, no
// RMW chain); pair-shared columns [wave][row][32 cols] -> bank = col =
// lane>>1, independent of r (always 2 lanes/bank = conflict-free); 768
// persistent blocks (3/CU, 51.7KB LDS); partials to d_ws; separate norm.

#define BINS 100
#define ROWS 101
#define BATCH 32
#define NPER 1048576
#define TPB 256
#define WAVES 4
#define COLS 32
#define BPR 24                         // blocks per row
#define GRID (BATCH * BPR)             // 768 = 3 per CU, all resident
#define NF4_ROW (NPER / 4)             // 262144 float4 per row
#define STRIDE (BPR * TPB)             // 6144 f4 grid stride
#define HCELLS (WAVES * ROWS * COLS)   // 12928 dwords = 51.7 KB

typedef float f32x4 __attribute__((ext_vector_type(4)));

__global__ __launch_bounds__(TPB, 3) void hist_kernel(const float* __restrict__ x,
                                                      float* __restrict__ partial) {
    __shared__ uint32_t h[HCELLS];
    const int tid = threadIdx.x;

    uint4* h4 = reinterpret_cast<uint4*>(h);
    for (int i = tid; i < HCELLS / 4; i += TPB) h4[i] = make_uint4(0, 0, 0, 0);
    __syncthreads();

    const int row  = blockIdx.x / BPR;
    const int jblk = blockIdx.x % BPR;
    const int wave = tid >> 6;
    const int col  = (tid & 63) >> 1;            // 2 lanes share a column
    uint32_t* hw = h + wave * (ROWS * COLS) + col;

    const f32x4* src = reinterpret_cast<const f32x4*>(x + (size_t)row * NPER);
    for (int i = jblk * TPB + tid; i < NF4_ROW; i += STRIDE) {
        f32x4 v = src[i];                        // cached vector load
#pragma unroll
        for (int e = 0; e < 4; ++e) {
            float U = __builtin_fmaf(v[e], 25600.0f, 128.0f);   // 256*(x*100+0.5)
            int  iU = (int)U;                                   // 128..25728
            int   r = iU >> 8;                                  // row 0..100
            uint32_t inc = 0x10000u | (uint32_t)(iU & 255);     // N=1 | Wfix
            atomicAdd(&hw[r * COLS], inc);       // ds_add_u32, bank = lane>>1
        }
    }
    __syncthreads();

    // Stage 1: per-(wave,row) sums over 32 cols (404 tasks; rotated col).
    // W-field carry: mean 108 hits/(wave,row), carry needs ~516 -> safe.
    uint32_t s0 = 0, s1 = 0;
    const int a0 = tid, a1 = tid + TPB;
    {
        int w = a0 / ROWS, r = a0 - w * ROWS;
        const uint32_t* base = h + w * (ROWS * COLS) + r * COLS;
        uint32_t s = 0;
#pragma unroll
        for (int c = 0; c < COLS; ++c) s += base[(c + tid) & (COLS - 1)];
        s0 = s;
    }
    if (a1 < WAVES * ROWS) {
        int w = a1 / ROWS, r = a1 - w * ROWS;
        const uint32_t* base = h + w * (ROWS * COLS) + r * COLS;
        uint32_t s = 0;
#pragma unroll
        for (int c = 0; c < COLS; ++c) s += base[(c + tid) & (COLS - 1)];
        s1 = s;
    }
    __syncthreads();
    // Stage 2: unpack task sums into reused h: N at [task], W at [512+task].
    h[a0] = s0 >> 16;
    h[512 + a0] = s0 & 0xFFFFu;
    if (a1 < WAVES * ROWS) { h[a1] = s1 >> 16; h[512 + a1] = s1 & 0xFFFFu; }
    __syncthreads();
    // Stage 3: per-row totals across the 4 waves.
    if (tid < ROWS) {
        uint32_t N = h[tid] + h[101 + tid] + h[202 + tid] + h[303 + tid];
        uint32_t W = h[512 + tid] + h[613 + tid] + h[714 + tid] + h[815 + tid];
        h[1024 + tid] = N;
        h[1536 + tid] = W;
    }
    __syncthreads();
    // Stage 4: counts[b] = N[b+1] - (W[b+1]-W[b])/256 -> partial store.
    if (tid < BINS) {
        float N1 = (float)h[1024 + tid + 1];
        float W1 = (float)h[1536 + tid + 1];
        float W0 = (float)h[1536 + tid];
        partial[blockIdx.x * BINS + tid] = N1 + (W0 - W1) * (1.0f / 256.0f);
    }
}

// Reduce 24 partials per row, normalize, write all of d_out (no init needed).
__global__ __launch_bounds__(128) void norm_kernel(const float* __restrict__ partial,
                                                   float* __restrict__ out) {
    __shared__ float sarr[2];
    const int row = blockIdx.x;
    const int t   = threadIdx.x;
    float cnt = 0.0f;
    if (t < BINS) {
        const float* p = partial + (size_t)row * BPR * BINS + t;
#pragma unroll
        for (int j = 0; j < BPR; ++j) cnt += p[j * BINS];
    }
    float s = cnt;
#pragma unroll
    for (int off = 32; off > 0; off >>= 1) s += __shfl_down(s, off);
    if ((t & 63) == 0) sarr[t >> 6] = s;
    __syncthreads();
    const float total = sarr[0] + sarr[1];
    if (t < BINS) {
        out[row * BINS + t] = 0.01f * cnt / (0.01f * total + 1e-5f);
    }
}

extern "C" void kernel_launch(void* const* d_in, const int* in_sizes, int n_in,
                              void* d_out, int out_size, void* d_ws, size_t ws_size,
                              hipStream_t stream) {
    const float* x = (const float*)d_in[0];
    float* out = (float*)d_out;
    float* partial = (float*)d_ws;     // 768*100*4 = 307.2 KB

    hist_kernel<<<GRID, TPB, 0, stream>>>(x, partial);
    norm_kernel<<<BATCH, 128, 0, stream>>>(partial, out);
}